// Round 1
// 336.717 us; speedup vs baseline: 1.0884x; 1.0884x over previous
//
#include <hip/hip_runtime.h>
#include <hip/hip_bf16.h>
#include <math.h>

#define BB 8
#define HH 128
#define WW 128
#define CC 96
#define NPIX (BB*HH*WW)
#define EPSF 1e-5f
#define FT_SMOOTH_F 1e-5f
#define ROWB 8320                 // 130 px x 64 B per LDS row
#define WELEM 82944               // 864*96 weight elements per conv

typedef short short8 __attribute__((ext_vector_type(8)));
typedef float f32x4 __attribute__((ext_vector_type(4)));

__device__ __forceinline__ float ftanimoto(float tpl, float tpp, float tll) {
    float num = tpl + FT_SMOOTH_F;
    float denum = 0.0f;
    float a = 1.0f;
#pragma unroll
    for (int d = 0; d < 5; ++d) {
        float bco = -(2.0f * a - 1.0f);
        denum += 1.0f / (a * (tpp + tll) + bco * tpl + FT_SMOOTH_F);
        a *= 2.0f;
    }
    return num * denum * 0.2f;
}

__device__ __forceinline__ unsigned short f2bf(float f) {
    __hip_bfloat16 h = __float2bfloat16(f);
    return *(unsigned short*)&h;
}

__device__ __forceinline__ float bf2f(unsigned short u) {
    return __uint_as_float((unsigned int)u << 16);
}

// ---------------------------------------------------------------------------
// Weight repack (all 3 convs, one dispatch): w fp32 [tap][ci][co] ->
// wT2 bf16 [cid][tap][cc][nt][lrow*4+qq][8j] so a B-fragment load is one
// contiguous 1 KB wave read.
// ---------------------------------------------------------------------------
__global__ __launch_bounds__(256) void cast_wT2(
    const float* __restrict__ wq, const float* __restrict__ wk,
    const float* __restrict__ wv, unsigned short* __restrict__ wT2)
{
    const int tid = blockIdx.x * 256 + threadIdx.x;
    if (tid >= 3 * WELEM) return;
    const int cid = tid / WELEM;
    const int o = tid - cid * WELEM;
    const int j = o & 7;
    const int rest = o >> 3;
    const int lq = rest & 63;
    const int lrow = lq >> 2, qq = lq & 3;
    const int tile = rest >> 6;          // (tap*3+cc)*6+nt
    const int nt = tile % 6;
    const int tcc = tile / 6;
    const int cc = tcc % 3, tap = tcc / 3;
    const int ci = cc * 32 + qq * 8 + j;
    const int co = nt * 16 + lrow;
    const float* w = (cid == 0) ? wq : (cid == 1) ? wk : wv;
    wT2[tid] = f2bf(w[(size_t)(tap * CC + ci) * CC + co]);
}

// ---------------------------------------------------------------------------
// Fused cast + implicit-GEMM 3x3 conv for q, k, v in ONE dispatch.
// T14 async-STAGE split: global loads for cc+1 are issued into registers
// BEFORE the 216-MFMA compute of cc, so the vmcnt drain at the barrier is
// covered by matrix work; the post-barrier stage is VALU+LDS only.
// ---------------------------------------------------------------------------
__global__ __launch_bounds__(256, 2) void conv_all(
    const float* __restrict__ x1, const float* __restrict__ x2,
    const float* __restrict__ x3, const unsigned short* __restrict__ wT2,
    const float* __restrict__ gq, const float* __restrict__ bq,
    const float* __restrict__ mq, const float* __restrict__ vq,
    const float* __restrict__ gk, const float* __restrict__ bk,
    const float* __restrict__ mk, const float* __restrict__ vk,
    const float* __restrict__ gv, const float* __restrict__ bv,
    const float* __restrict__ mv, const float* __restrict__ vv,
    unsigned short* __restrict__ qb, unsigned short* __restrict__ kb,
    unsigned short* __restrict__ vb)
{
    __shared__ __align__(16) char smem[4 * ROWB];     // 33,280 B
    const int tid = threadIdx.x;
    const int wvi = tid >> 6;
    const int L  = tid & 63;
    const int cid = blockIdx.x >> 9;                  // 0:q 1:k 2:v
    const int blk = blockIdx.x & 511;
    const int b  = blk >> 6;
    const int h0 = (blk & 63) << 1;
    const int hrow = h0 + (wvi >> 1);
    const int wwbase = (wvi & 1) << 6;
    const int lrow = L & 15;
    const int qq = L >> 4;

    const float* xsrc = (cid == 0) ? x1 : (cid == 1) ? x2 : x3;
    const unsigned short* wT2p = wT2 + (size_t)cid * WELEM;

    // staging: wave wvi stages LDS row wvi <- input image row h0-1+wvi
    const int hst = h0 - 1 + wvi;
    const bool stv = (hst >= 0) && (hst < HH);
    const float* xrow = xsrc + (size_t)(b * HH + (stv ? hst : 0)) * WW * CC;
    char* myrow = smem + wvi * ROWB;

    f32x4 acc[4][6];
#pragma unroll
    for (int mt = 0; mt < 4; ++mt)
#pragma unroll
        for (int nt = 0; nt < 6; ++nt) acc[mt][nt] = (f32x4){0.f, 0.f, 0.f, 0.f};

    float4 pre[9][2];                                 // prefetch registers (T14)

#define PREF(ccv) do { if (stv) { _Pragma("unroll") \
    for (int it = 0; it < 9; ++it) { \
        const int idx = it * 64 + L; \
        if (idx < 520) { \
            const int p = idx >> 2; \
            const int c = idx & 3; \
            const int w = p - 1; \
            if (w >= 0 && w < WW) { \
                const float* src = xrow + (size_t)w * CC + (ccv) * 32 + c * 8; \
                pre[it][0] = *(const float4*)src; \
                pre[it][1] = *(const float4*)(src + 4); \
            } } } } } while (0)

#define WST() do { if (stv) { _Pragma("unroll") \
    for (int it = 0; it < 9; ++it) { \
        const int idx = it * 64 + L; \
        if (idx < 520) { \
            const int p = idx >> 2; \
            const int c = idx & 3; \
            const int w = p - 1; \
            short8 o = (short8){0,0,0,0,0,0,0,0}; \
            if (w >= 0 && w < WW) { \
                o[0] = (short)f2bf(pre[it][0].x); o[1] = (short)f2bf(pre[it][0].y); \
                o[2] = (short)f2bf(pre[it][0].z); o[3] = (short)f2bf(pre[it][0].w); \
                o[4] = (short)f2bf(pre[it][1].x); o[5] = (short)f2bf(pre[it][1].y); \
                o[6] = (short)f2bf(pre[it][1].z); o[7] = (short)f2bf(pre[it][1].w); \
            } \
            const int slot = c ^ ((p ^ (p >> 2)) & 3); \
            *(short8*)(myrow + p * 64 + slot * 16) = o; \
        } } } } while (0)

#define COMPUTE(ccv) do { _Pragma("unroll") \
    for (int dy = -1; dy <= 1; ++dy) { \
        const int hh = hrow + dy; \
        if (hh < 0 || hh >= HH) continue; \
        const char* ldsrow = smem + (dy + 1 + (wvi >> 1)) * ROWB; \
        _Pragma("unroll") \
        for (int dx = -1; dx <= 1; ++dx) { \
            const int tap = (dy + 1) * 3 + (dx + 1); \
            const unsigned short* bsrc = wT2p + (size_t)(tap * 3 + (ccv)) * 6 * 512; \
            short8 bfr[6]; \
            _Pragma("unroll") \
            for (int nt = 0; nt < 6; ++nt) \
                bfr[nt] = *(const short8*)(bsrc + nt * 512 + (lrow * 4 + qq) * 8); \
            short8 afr[4]; \
            _Pragma("unroll") \
            for (int mt = 0; mt < 4; ++mt) { \
                const int p = wwbase + mt * 16 + lrow + dx + 1; \
                const int slot = qq ^ ((p ^ (p >> 2)) & 3); \
                afr[mt] = *(const short8*)(ldsrow + p * 64 + slot * 16); \
            } \
            _Pragma("unroll") \
            for (int nt = 0; nt < 6; ++nt) \
                _Pragma("unroll") \
                for (int mt = 0; mt < 4; ++mt) \
                    acc[mt][nt] = __builtin_amdgcn_mfma_f32_16x16x32_bf16( \
                        afr[mt], bfr[nt], acc[mt][nt], 0, 0, 0); \
        } } } while (0)

    PREF(0);
    WST();                      // vmcnt drains here (nothing else to do yet)
    __syncthreads();
    PREF(1);                    // in flight across COMPUTE(0)
    COMPUTE(0);
    __syncthreads();
    WST();                      // loads long since landed: VALU+LDS only
    __syncthreads();
    PREF(2);                    // in flight across COMPUTE(1)
    COMPUTE(1);
    __syncthreads();
    WST();
    __syncthreads();
    COMPUTE(2);

#undef PREF
#undef WST
#undef COMPUTE

    const float* g  = (cid == 0) ? gq : (cid == 1) ? gk : gv;
    const float* bt = (cid == 0) ? bq : (cid == 1) ? bk : bv;
    const float* mu = (cid == 0) ? mq : (cid == 1) ? mk : mv;
    const float* var = (cid == 0) ? vq : (cid == 1) ? vk : vv;
    unsigned short* outp = (cid == 0) ? qb : (cid == 1) ? kb : vb;

    // epilogue: C layout col=lane&15, row=(lane>>4)*4+reg
#pragma unroll
    for (int nt = 0; nt < 6; ++nt) {
        const int co = nt * 16 + lrow;
        const float scl = g[co] * rsqrtf(var[co] + EPSF);
        const float sft = bt[co] - mu[co] * scl;
#pragma unroll
        for (int mt = 0; mt < 4; ++mt) {
#pragma unroll
            for (int r = 0; r < 4; ++r) {
                const int row = (wvi << 6) + (mt << 4) + (qq << 2) + r;
                const int h = h0 + (row >> 7);
                const int w = row & 127;
                const size_t pix = (size_t)(b * HH + h) * WW + w;
                const float t = acc[mt][nt][r] * scl + sft;
                outp[pix * CC + co] = f2bf(1.0f / (1.0f + expf(-t)));
            }
        }
    }
}

// ---------------------------------------------------------------------------
// Fused attention sums: ONE pass over q,k computes BOTH the per-pixel
// (spatial) Tanimoto terms and the per-channel (channel) partial sums.
// 512 blocks x 192 threads; block = 256-pixel slab. Thread (g,c8) loads
// 16 pixels x 8 channels coalesced; per-pixel partials go to LDS for the
// spatial reduce, per-channel partials to LDS for the channel reduce.
// ---------------------------------------------------------------------------
__global__ __launch_bounds__(192) void qk_att(
    const unsigned short* __restrict__ qb, const unsigned short* __restrict__ kb,
    float* __restrict__ atts, float* __restrict__ part)
{
    __shared__ float pxr[256][37];       // [px][c8*3+comp], pad 37 vs 36 for banks
    __shared__ float red[16][12][24];
    const int t = threadIdx.x;
    const int g = t / 12;
    const int c8 = t - g * 12;
    const size_t p0 = (size_t)blockIdx.x * 256;

    float s_tpl[8], s_tpp[8], s_tll[8];
#pragma unroll
    for (int j = 0; j < 8; ++j) { s_tpl[j] = 0.f; s_tpp[j] = 0.f; s_tll[j] = 0.f; }

#pragma unroll
    for (int i = 0; i < 16; ++i) {
        const int px = g + i * 16;
        const size_t pe = (p0 + px) * CC + c8 * 8;
        const short8 qv = *(const short8*)(qb + pe);
        const short8 kv = *(const short8*)(kb + pe);
        float ptpl = 0.f, ptpp = 0.f, ptll = 0.f;
#pragma unroll
        for (int j = 0; j < 8; ++j) {
            const float qf = bf2f((unsigned short)qv[j]);
            const float kf = bf2f((unsigned short)kv[j]);
            s_tpl[j] = fmaf(qf, kf, s_tpl[j]);
            s_tpp[j] = fmaf(qf, qf, s_tpp[j]);
            s_tll[j] = fmaf(kf, kf, s_tll[j]);
            ptpl = fmaf(qf, kf, ptpl);
            ptpp = fmaf(qf, qf, ptpp);
            ptll = fmaf(kf, kf, ptll);
        }
        pxr[px][c8 * 3 + 0] = ptpl;
        pxr[px][c8 * 3 + 1] = ptpp;
        pxr[px][c8 * 3 + 2] = ptll;
    }
#pragma unroll
    for (int j = 0; j < 8; ++j) {
        red[g][c8][j]      = s_tpl[j];
        red[g][c8][8 + j]  = s_tpp[j];
        red[g][c8][16 + j] = s_tll[j];
    }
    __syncthreads();

    // spatial attention: one thread per pixel (t, then t+192)
    for (int px = t; px < 256; px += 192) {
        float tpl = 0.f, tpp = 0.f, tll = 0.f;
#pragma unroll
        for (int c = 0; c < 12; ++c) {
            tpl += pxr[px][c * 3 + 0];
            tpp += pxr[px][c * 3 + 1];
            tll += pxr[px][c * 3 + 2];
        }
        atts[p0 + px] = ftanimoto(tpl, tpp, tll);
    }

    // channel partials for this slab
    if (t < CC) {
        const int cg = t >> 3, cj = t & 7;
        float tpl = 0.f, tpp = 0.f, tll = 0.f;
        for (int gg = 0; gg < 16; ++gg) {
            tpl += red[gg][cg][cj];
            tpp += red[gg][cg][8 + cj];
            tll += red[gg][cg][16 + cj];
        }
        const size_t idx = ((size_t)blockIdx.x * CC + t) * 3;
        part[idx + 0] = tpl;
        part[idx + 1] = tpp;
        part[idx + 2] = tll;
    }
}

// ---------------------------------------------------------------------------
// Channel attention stage 2: one wave per (b,c) pair (768 waves), lane s
// holds slab s's partial, butterfly shuffle reduce. Replaces the 8-block
// serial reduce (16 waves chip-wide, pure latency).
// ---------------------------------------------------------------------------
__global__ __launch_bounds__(256) void chan_final2(
    const float* __restrict__ part, float* __restrict__ attc)
{
    const int wid = blockIdx.x * 4 + (threadIdx.x >> 6);   // 0..767
    const int lane = threadIdx.x & 63;
    const int b = wid / CC;
    const int c = wid - b * CC;
    const size_t idx = (((size_t)b * 64 + lane) * CC + c) * 3;
    float tpl = part[idx + 0];
    float tpp = part[idx + 1];
    float tll = part[idx + 2];
#pragma unroll
    for (int off = 32; off > 0; off >>= 1) {
        tpl += __shfl_xor(tpl, off);
        tpp += __shfl_xor(tpp, off);
        tll += __shfl_xor(tll, off);
    }
    if (lane == 0) attc[b * CC + c] = ftanimoto(tpl, tpp, tll);
}

// ---------------------------------------------------------------------------
// Final combine: out = bn(0.5*(attc+atts)*v). Reads v bf16, writes fp32.
// ---------------------------------------------------------------------------
__global__ __launch_bounds__(256) void final_combine(
    const unsigned short* __restrict__ vb, const float* __restrict__ atts,
    const float* __restrict__ attc,
    const float* __restrict__ gn, const float* __restrict__ bnb,
    const float* __restrict__ mn, const float* __restrict__ vn,
    float* __restrict__ out)
{
    const int tid = blockIdx.x * 256 + threadIdx.x;   // NPIX*12 jobs
    const int c8 = tid % 12;
    const int pix = tid / 12;
    const int b = pix >> 14;                          // HH*WW = 16384
    const short8 v = *(const short8*)(vb + (size_t)pix * CC + c8 * 8);
    const float as = atts[pix];
    float r[8];
#pragma unroll
    for (int j = 0; j < 8; ++j) {
        const int co = c8 * 8 + j;
        const float nscl = gn[co] * rsqrtf(vn[co] + EPSF);
        const float nsft = bnb[co] - mn[co] * nscl;
        const float att = 0.5f * (attc[b * CC + co] + as);
        r[j] = att * bf2f((unsigned short)v[j]) * nscl + nsft;
    }
    float* dst = out + (size_t)pix * CC + c8 * 8;
    *(float4*)dst = make_float4(r[0], r[1], r[2], r[3]);
    *(float4*)(dst + 4) = make_float4(r[4], r[5], r[6], r[7]);
}

extern "C" void kernel_launch(void* const* d_in, const int* in_sizes, int n_in,
                              void* d_out, int out_size, void* d_ws, size_t ws_size,
                              hipStream_t stream)
{
    const float* x1 = (const float*)d_in[0];
    const float* x2 = (const float*)d_in[1];
    const float* x3 = (const float*)d_in[2];
    const float* wq = (const float*)d_in[3];
    const float* gq = (const float*)d_in[4];
    const float* bq = (const float*)d_in[5];
    const float* mq = (const float*)d_in[6];
    const float* vq = (const float*)d_in[7];
    const float* wk = (const float*)d_in[8];
    const float* gk = (const float*)d_in[9];
    const float* bk = (const float*)d_in[10];
    const float* mk = (const float*)d_in[11];
    const float* vk = (const float*)d_in[12];
    const float* wvw = (const float*)d_in[13];
    const float* gv = (const float*)d_in[14];
    const float* bv = (const float*)d_in[15];
    const float* mv = (const float*)d_in[16];
    const float* vv = (const float*)d_in[17];
    const float* gn = (const float*)d_in[18];
    const float* bnb = (const float*)d_in[19];
    const float* mn = (const float*)d_in[20];
    const float* vn = (const float*)d_in[21];

    // workspace (~27 MB): wT2 | vb | atts | part | attc
    unsigned short* wT2 = (unsigned short*)d_ws;                  // 3*82944 bf16
    unsigned short* vb = wT2 + (size_t)3 * WELEM;                 // NPIX*96 bf16
    float* atts = (float*)(vb + (size_t)NPIX * CC);               // NPIX fp32
    float* part = atts + NPIX;                                    // 512*96*3
    float* attc = part + (size_t)512 * CC * 3;                    // 768

    // q,k bf16 exactly fill d_out; dead before final_combine writes fp32
    unsigned short* qb = (unsigned short*)d_out;
    unsigned short* kb = qb + (size_t)NPIX * CC;

    cast_wT2<<<(3 * WELEM + 255) / 256, 256, 0, stream>>>(wq, wk, wvw, wT2);
    conv_all<<<1536, 256, 0, stream>>>(x1, x2, x3, wT2,
                                       gq, bq, mq, vq, gk, bk, mk, vk,
                                       gv, bv, mv, vv, qb, kb, vb);
    qk_att<<<NPIX / 256, 192, 0, stream>>>(qb, kb, atts, part);
    chan_final2<<<192, 256, 0, stream>>>(part, attc);
    final_combine<<<NPIX * 12 / 256, 256, 0, stream>>>(vb, atts, attc,
                                                       gn, bnb, mn, vn,
                                                       (float*)d_out);
}

// Round 2
// 325.963 us; speedup vs baseline: 1.1243x; 1.0330x over previous
//
#include <hip/hip_runtime.h>
#include <hip/hip_bf16.h>
#include <math.h>

#define BB 8
#define HH 128
#define WW 128
#define CC 96
#define NPIX (BB*HH*WW)
#define EPSF 1e-5f
#define FT_SMOOTH_F 1e-5f
#define ROWB 8320                 // 130 px x 64 B per LDS row
#define WELEM 82944               // 864*96 weight elements per conv

typedef short short8 __attribute__((ext_vector_type(8)));
typedef float f32x4 __attribute__((ext_vector_type(4)));

__device__ __forceinline__ float ftanimoto(float tpl, float tpp, float tll) {
    float num = tpl + FT_SMOOTH_F;
    float denum = 0.0f;
    float a = 1.0f;
#pragma unroll
    for (int d = 0; d < 5; ++d) {
        float bco = -(2.0f * a - 1.0f);
        denum += 1.0f / (a * (tpp + tll) + bco * tpl + FT_SMOOTH_F);
        a *= 2.0f;
    }
    return num * denum * 0.2f;
}

__device__ __forceinline__ unsigned short f2bf(float f) {
    __hip_bfloat16 h = __float2bfloat16(f);
    return *(unsigned short*)&h;
}

__device__ __forceinline__ float bf2f(unsigned short u) {
    return __uint_as_float((unsigned int)u << 16);
}

// ---------------------------------------------------------------------------
// Weight repack (all 3 convs, one dispatch): w fp32 [tap][ci][co] ->
// wT2 bf16 [cid][tap][cc][nt][lrow*4+qq][8j] so a B-fragment load is one
// contiguous 1 KB wave read.
// ---------------------------------------------------------------------------
__global__ __launch_bounds__(256) void cast_wT2(
    const float* __restrict__ wq, const float* __restrict__ wk,
    const float* __restrict__ wv, unsigned short* __restrict__ wT2)
{
    const int tid = blockIdx.x * 256 + threadIdx.x;
    if (tid >= 3 * WELEM) return;
    const int cid = tid / WELEM;
    const int o = tid - cid * WELEM;
    const int j = o & 7;
    const int rest = o >> 3;
    const int lq = rest & 63;
    const int lrow = lq >> 2, qq = lq & 3;
    const int tile = rest >> 6;          // (tap*3+cc)*6+nt
    const int nt = tile % 6;
    const int tcc = tile / 6;
    const int cc = tcc % 3, tap = tcc / 3;
    const int ci = cc * 32 + qq * 8 + j;
    const int co = nt * 16 + lrow;
    const float* w = (cid == 0) ? wq : (cid == 1) ? wk : wv;
    wT2[tid] = f2bf(w[(size_t)(tap * CC + ci) * CC + co]);
}

// ---------------------------------------------------------------------------
// Fused cast + implicit-GEMM 3x3 conv for q, k, v in ONE dispatch.
// (Round-0 proven structure: occupancy-based latency hiding, 80 VGPR,
// 3 blocks/CU target. Round-1's register prefetch regressed — reverted.)
// Epilogue sigmoid now uses raw v_exp_f32 + v_rcp_f32 (bf16 output makes
// the ~1ulp approx error invisible).
// ---------------------------------------------------------------------------
__global__ __launch_bounds__(256, 3) void conv_all(
    const float* __restrict__ x1, const float* __restrict__ x2,
    const float* __restrict__ x3, const unsigned short* __restrict__ wT2,
    const float* __restrict__ gq, const float* __restrict__ bq,
    const float* __restrict__ mq, const float* __restrict__ vq,
    const float* __restrict__ gk, const float* __restrict__ bk,
    const float* __restrict__ mk, const float* __restrict__ vk,
    const float* __restrict__ gv, const float* __restrict__ bv,
    const float* __restrict__ mv, const float* __restrict__ vv,
    unsigned short* __restrict__ qb, unsigned short* __restrict__ kb,
    unsigned short* __restrict__ vb)
{
    __shared__ __align__(16) char smem[4 * ROWB];     // 33,280 B
    const int tid = threadIdx.x;
    const int wv = tid >> 6;
    const int L  = tid & 63;
    const int cid = blockIdx.x >> 9;                  // 0:q 1:k 2:v
    const int blk = blockIdx.x & 511;
    const int b  = blk >> 6;
    const int h0 = (blk & 63) << 1;
    const int hrow = h0 + (wv >> 1);
    const int wwbase = (wv & 1) << 6;
    const int lrow = L & 15;
    const int qq = L >> 4;

    const float* xsrc = (cid == 0) ? x1 : (cid == 1) ? x2 : x3;
    const unsigned short* wT2p = wT2 + (size_t)cid * WELEM;

    // staging: wave wv stages LDS row wv <- input image row h0-1+wv
    const int hst = h0 - 1 + wv;
    const bool stv = (hst >= 0) && (hst < HH);
    const float* xrow = xsrc + (size_t)(b * HH + (stv ? hst : 0)) * WW * CC;
    char* myrow = smem + wv * ROWB;

    f32x4 acc[4][6];
#pragma unroll
    for (int mt = 0; mt < 4; ++mt)
#pragma unroll
        for (int nt = 0; nt < 6; ++nt) acc[mt][nt] = (f32x4){0.f, 0.f, 0.f, 0.f};

    for (int cc = 0; cc < 3; ++cc) {
        __syncthreads();                              // LDS safe to overwrite
        if (stv) {
#pragma unroll
            for (int it = 0; it < 9; ++it) {
                const int idx = it * 64 + L;          // chunk job: 130 px x 4 chunks
                if (idx < 520) {
                    const int p = idx >> 2;           // lds pixel slot 0..129
                    const int c = idx & 3;            // 8-elem chunk
                    const int w = p - 1;              // image w = -1..128
                    short8 o = (short8){0,0,0,0,0,0,0,0};
                    if (w >= 0 && w < WW) {
                        const float* src = xrow + (size_t)w * CC + cc * 32 + c * 8;
                        const float4 a0 = *(const float4*)src;
                        const float4 a1 = *(const float4*)(src + 4);
                        o[0] = (short)f2bf(a0.x); o[1] = (short)f2bf(a0.y);
                        o[2] = (short)f2bf(a0.z); o[3] = (short)f2bf(a0.w);
                        o[4] = (short)f2bf(a1.x); o[5] = (short)f2bf(a1.y);
                        o[6] = (short)f2bf(a1.z); o[7] = (short)f2bf(a1.w);
                    }
                    const int slot = c ^ ((p ^ (p >> 2)) & 3);
                    *(short8*)(myrow + p * 64 + slot * 16) = o;
                }
            }
        }
        __syncthreads();                              // staging visible
#pragma unroll
        for (int dy = -1; dy <= 1; ++dy) {
            const int hh = hrow + dy;
            if (hh < 0 || hh >= HH) continue;         // wave-uniform skip
            const char* ldsrow = smem + (dy + 1 + (wv >> 1)) * ROWB;
#pragma unroll
            for (int dx = -1; dx <= 1; ++dx) {
                const int tap = (dy + 1) * 3 + (dx + 1);
                const unsigned short* bsrc = wT2p + (size_t)(tap * 3 + cc) * 6 * 512;
                short8 bf[6];
#pragma unroll
                for (int nt = 0; nt < 6; ++nt)
                    bf[nt] = *(const short8*)(bsrc + nt * 512 + (lrow * 4 + qq) * 8);
                short8 af[4];
#pragma unroll
                for (int mt = 0; mt < 4; ++mt) {
                    const int p = wwbase + mt * 16 + lrow + dx + 1;
                    const int slot = qq ^ ((p ^ (p >> 2)) & 3);
                    af[mt] = *(const short8*)(ldsrow + p * 64 + slot * 16);
                }
#pragma unroll
                for (int nt = 0; nt < 6; ++nt)
#pragma unroll
                    for (int mt = 0; mt < 4; ++mt)
                        acc[mt][nt] = __builtin_amdgcn_mfma_f32_16x16x32_bf16(
                            af[mt], bf[nt], acc[mt][nt], 0, 0, 0);
            }
        }
    }

    const float* g  = (cid == 0) ? gq : (cid == 1) ? gk : gv;
    const float* bt = (cid == 0) ? bq : (cid == 1) ? bk : bv;
    const float* mu = (cid == 0) ? mq : (cid == 1) ? mk : mv;
    const float* var = (cid == 0) ? vq : (cid == 1) ? vk : vv;
    unsigned short* outp = (cid == 0) ? qb : (cid == 1) ? kb : vb;

    // epilogue: C layout col=lane&15, row=(lane>>4)*4+reg
#pragma unroll
    for (int nt = 0; nt < 6; ++nt) {
        const int co = nt * 16 + lrow;
        const float scl = g[co] * rsqrtf(var[co] + EPSF);
        const float sft = bt[co] - mu[co] * scl;
#pragma unroll
        for (int mt = 0; mt < 4; ++mt) {
#pragma unroll
            for (int r = 0; r < 4; ++r) {
                const int row = (wv << 6) + (mt << 4) + (qq << 2) + r;
                const int h = h0 + (row >> 7);
                const int w = row & 127;
                const size_t pix = (size_t)(b * HH + h) * WW + w;
                const float t = acc[mt][nt][r] * scl + sft;
                const float e = __builtin_amdgcn_exp2f(t * -1.442695041f);
                outp[pix * CC + co] = f2bf(__builtin_amdgcn_rcpf(1.0f + e));
            }
        }
    }
}

// ---------------------------------------------------------------------------
// Fused attention sums: ONE pass over q,k computes BOTH the per-pixel
// (spatial) Tanimoto terms and the per-channel (channel) partial sums.
// 1024 blocks x 192 threads; block = 128-pixel slab (was 256: LDS 56K ->
// 37.4K, 2 -> 4 blocks/CU, serial loop 16 -> 8 deep).
// ---------------------------------------------------------------------------
__global__ __launch_bounds__(192) void qk_att(
    const unsigned short* __restrict__ qb, const unsigned short* __restrict__ kb,
    float* __restrict__ atts, float* __restrict__ part)
{
    __shared__ float pxr[128][37];       // [px][c8*3+comp], pad 37 vs 36 for banks
    __shared__ float red[16][12][24];
    const int t = threadIdx.x;
    const int g = t / 12;
    const int c8 = t - g * 12;
    const size_t p0 = (size_t)blockIdx.x * 128;

    float s_tpl[8], s_tpp[8], s_tll[8];
#pragma unroll
    for (int j = 0; j < 8; ++j) { s_tpl[j] = 0.f; s_tpp[j] = 0.f; s_tll[j] = 0.f; }

#pragma unroll
    for (int i = 0; i < 8; ++i) {
        const int px = g + i * 16;
        const size_t pe = (p0 + px) * CC + c8 * 8;
        const short8 qv = *(const short8*)(qb + pe);
        const short8 kv = *(const short8*)(kb + pe);
        float ptpl = 0.f, ptpp = 0.f, ptll = 0.f;
#pragma unroll
        for (int j = 0; j < 8; ++j) {
            const float qf = bf2f((unsigned short)qv[j]);
            const float kf = bf2f((unsigned short)kv[j]);
            s_tpl[j] = fmaf(qf, kf, s_tpl[j]);
            s_tpp[j] = fmaf(qf, qf, s_tpp[j]);
            s_tll[j] = fmaf(kf, kf, s_tll[j]);
            ptpl = fmaf(qf, kf, ptpl);
            ptpp = fmaf(qf, qf, ptpp);
            ptll = fmaf(kf, kf, ptll);
        }
        pxr[px][c8 * 3 + 0] = ptpl;
        pxr[px][c8 * 3 + 1] = ptpp;
        pxr[px][c8 * 3 + 2] = ptll;
    }
#pragma unroll
    for (int j = 0; j < 8; ++j) {
        red[g][c8][j]      = s_tpl[j];
        red[g][c8][8 + j]  = s_tpp[j];
        red[g][c8][16 + j] = s_tll[j];
    }
    __syncthreads();

    // spatial attention: one thread per pixel (threads 0..127)
    if (t < 128) {
        float tpl = 0.f, tpp = 0.f, tll = 0.f;
#pragma unroll
        for (int c = 0; c < 12; ++c) {
            tpl += pxr[t][c * 3 + 0];
            tpp += pxr[t][c * 3 + 1];
            tll += pxr[t][c * 3 + 2];
        }
        atts[p0 + t] = ftanimoto(tpl, tpp, tll);
    }

    // channel partials for this slab
    if (t < CC) {
        const int cg = t >> 3, cj = t & 7;
        float tpl = 0.f, tpp = 0.f, tll = 0.f;
        for (int gg = 0; gg < 16; ++gg) {
            tpl += red[gg][cg][cj];
            tpp += red[gg][cg][8 + cj];
            tll += red[gg][cg][16 + cj];
        }
        const size_t idx = ((size_t)blockIdx.x * CC + t) * 3;
        part[idx + 0] = tpl;
        part[idx + 1] = tpp;
        part[idx + 2] = tll;
    }
}

// ---------------------------------------------------------------------------
// Channel attention stage 2: one wave per (b,c) pair (768 waves); lane s
// sums slabs s and s+64 (128 slabs/batch now), butterfly shuffle reduce.
// ---------------------------------------------------------------------------
__global__ __launch_bounds__(256) void chan_final2(
    const float* __restrict__ part, float* __restrict__ attc)
{
    const int wid = blockIdx.x * 4 + (threadIdx.x >> 6);   // 0..767
    const int lane = threadIdx.x & 63;
    const int b = wid / CC;
    const int c = wid - b * CC;
    const size_t base = (((size_t)b * 128 + lane) * CC + c) * 3;
    const size_t off = (size_t)64 * CC * 3;
    float tpl = part[base + 0] + part[base + off + 0];
    float tpp = part[base + 1] + part[base + off + 1];
    float tll = part[base + 2] + part[base + off + 2];
#pragma unroll
    for (int off2 = 32; off2 > 0; off2 >>= 1) {
        tpl += __shfl_xor(tpl, off2);
        tpp += __shfl_xor(tpp, off2);
        tll += __shfl_xor(tll, off2);
    }
    if (lane == 0) attc[b * CC + c] = ftanimoto(tpl, tpp, tll);
}

// ---------------------------------------------------------------------------
// Final combine: out = bn(0.5*(attc+atts)*v). Reads v bf16, writes fp32.
// ---------------------------------------------------------------------------
__global__ __launch_bounds__(256) void final_combine(
    const unsigned short* __restrict__ vb, const float* __restrict__ atts,
    const float* __restrict__ attc,
    const float* __restrict__ gn, const float* __restrict__ bnb,
    const float* __restrict__ mn, const float* __restrict__ vn,
    float* __restrict__ out)
{
    const int tid = blockIdx.x * 256 + threadIdx.x;   // NPIX*12 jobs
    const int c8 = tid % 12;
    const int pix = tid / 12;
    const int b = pix >> 14;                          // HH*WW = 16384
    const short8 v = *(const short8*)(vb + (size_t)pix * CC + c8 * 8);
    const float as = atts[pix];
    float r[8];
#pragma unroll
    for (int j = 0; j < 8; ++j) {
        const int co = c8 * 8 + j;
        const float nscl = gn[co] * rsqrtf(vn[co] + EPSF);
        const float nsft = bnb[co] - mn[co] * nscl;
        const float att = 0.5f * (attc[b * CC + co] + as);
        r[j] = att * bf2f((unsigned short)v[j]) * nscl + nsft;
    }
    float* dst = out + (size_t)pix * CC + c8 * 8;
    *(float4*)dst = make_float4(r[0], r[1], r[2], r[3]);
    *(float4*)(dst + 4) = make_float4(r[4], r[5], r[6], r[7]);
}

extern "C" void kernel_launch(void* const* d_in, const int* in_sizes, int n_in,
                              void* d_out, int out_size, void* d_ws, size_t ws_size,
                              hipStream_t stream)
{
    const float* x1 = (const float*)d_in[0];
    const float* x2 = (const float*)d_in[1];
    const float* x3 = (const float*)d_in[2];
    const float* wq = (const float*)d_in[3];
    const float* gq = (const float*)d_in[4];
    const float* bq = (const float*)d_in[5];
    const float* mq = (const float*)d_in[6];
    const float* vq = (const float*)d_in[7];
    const float* wk = (const float*)d_in[8];
    const float* gk = (const float*)d_in[9];
    const float* bk = (const float*)d_in[10];
    const float* mk = (const float*)d_in[11];
    const float* vk = (const float*)d_in[12];
    const float* wvw = (const float*)d_in[13];
    const float* gv = (const float*)d_in[14];
    const float* bv = (const float*)d_in[15];
    const float* mv = (const float*)d_in[16];
    const float* vv = (const float*)d_in[17];
    const float* gn = (const float*)d_in[18];
    const float* bnb = (const float*)d_in[19];
    const float* mn = (const float*)d_in[20];
    const float* vn = (const float*)d_in[21];

    // workspace (~28 MB): wT2 | vb | atts | part | attc
    unsigned short* wT2 = (unsigned short*)d_ws;                  // 3*82944 bf16
    unsigned short* vb = wT2 + (size_t)3 * WELEM;                 // NPIX*96 bf16
    float* atts = (float*)(vb + (size_t)NPIX * CC);               // NPIX fp32
    float* part = atts + NPIX;                                    // 1024*96*3
    float* attc = part + (size_t)1024 * CC * 3;                   // 768

    // q,k bf16 exactly fill d_out; dead before final_combine writes fp32
    unsigned short* qb = (unsigned short*)d_out;
    unsigned short* kb = qb + (size_t)NPIX * CC;

    cast_wT2<<<(3 * WELEM + 255) / 256, 256, 0, stream>>>(wq, wk, wvw, wT2);
    conv_all<<<1536, 256, 0, stream>>>(x1, x2, x3, wT2,
                                       gq, bq, mq, vq, gk, bk, mk, vk,
                                       gv, bv, mv, vv, qb, kb, vb);
    qk_att<<<NPIX / 128, 192, 0, stream>>>(qb, kb, atts, part);
    chan_final2<<<192, 256, 0, stream>>>(part, attc);
    final_combine<<<NPIX * 12 / 256, 256, 0, stream>>>(vb, atts, attc,
                                                       gn, bnb, mn, vn,
                                                       (float*)d_out);
}